// Round 5
// baseline (628.934 us; speedup 1.0000x reference)
//
#include <hip/hip_runtime.h>

// ProbAttention on MI355X (gfx950). Inputs/outputs fp32; compute in bf16 MFMA
// (mfma_f32_16x16x32_bf16, fp32 accumulate). B=8, L=4096, D=512, H=8, DK=64,
// S=512, CONV_K=3, POOL=2.
//
// Pipeline:
//  0. cvt: x (fp32) -> xb (bf16)
//  1. weight transposes fp32 -> bf16 Bt[N][K]
//  2. gather xb rows: xkg (K path, double-gather collapsed), xvg (V path)
//  3. Kg = xkg @ Wk, Vg = xvg @ Wv  (bf16 GEMM)
//  4. Vt[b][e][s] = Vg[b][s][e]
//  5. fused attn v3: BARRIER-FREE flash (transposed scores, register softmax,
//     wave-private LDS only) -> Pad[b][l+1][e]
//  6. conv-as-GEMM K=1536 + bias + ELU + MaxPool2 -> Pool
//  7. final GEMM + bias -> out (fp32)

typedef __attribute__((ext_vector_type(8))) short  short8;
typedef __attribute__((ext_vector_type(4))) short  short4b;
typedef __attribute__((ext_vector_type(4))) float  f32x4;

#define LSEQ   4096
#define SK     512
#define EDIM   512
#define LPAD   4098            // L + 2
#define PADROW 2098176         // LPAD * 512 (shorts)

static __device__ __forceinline__ float bf2f(unsigned short h) {
    union { unsigned int u; float f; } v; v.u = ((unsigned int)h) << 16; return v.f;
}
static __device__ __forceinline__ unsigned short f2bf(float f) {
    union { float f; unsigned int u; } v; v.f = f;
    unsigned int r = (v.u + 0x7fffu + ((v.u >> 16) & 1u)) >> 16;
    return (unsigned short)r;
}

// ---------------------------------------------------------------- fp32 -> bf16
__global__ __launch_bounds__(256)
void cvt_bf16(const float* __restrict__ src, unsigned short* __restrict__ dst)
{
    const size_t i = ((size_t)blockIdx.x * 256 + threadIdx.x) * 8;
    const float4 a = *(const float4*)(src + i);
    const float4 b = *(const float4*)(src + i + 4);
    short8 o;
    o[0] = (short)f2bf(a.x); o[1] = (short)f2bf(a.y);
    o[2] = (short)f2bf(a.z); o[3] = (short)f2bf(a.w);
    o[4] = (short)f2bf(b.x); o[5] = (short)f2bf(b.y);
    o[6] = (short)f2bf(b.z); o[7] = (short)f2bf(b.w);
    *(short8*)(dst + i) = o;
}

// ---------------------------------------------------------------- transpose fp32 -> bf16
__global__ __launch_bounds__(256)
void tr_f32_bf16(unsigned short* __restrict__ dst, const float* __restrict__ src,
                 int R, int C)
{
    __shared__ unsigned short T[64][72];
    const int t  = threadIdx.x;
    const int r0 = blockIdx.y * 64, c0 = blockIdx.x * 64;
    const int row = t >> 2, cg = (t & 3) * 16;
    const float* s = src + (size_t)(r0 + row) * C + c0 + cg;
    const float4 f0 = *(const float4*)s;
    const float4 f1 = *(const float4*)(s + 4);
    const float4 f2 = *(const float4*)(s + 8);
    const float4 f3 = *(const float4*)(s + 12);
    T[row][cg + 0]  = f2bf(f0.x); T[row][cg + 1]  = f2bf(f0.y);
    T[row][cg + 2]  = f2bf(f0.z); T[row][cg + 3]  = f2bf(f0.w);
    T[row][cg + 4]  = f2bf(f1.x); T[row][cg + 5]  = f2bf(f1.y);
    T[row][cg + 6]  = f2bf(f1.z); T[row][cg + 7]  = f2bf(f1.w);
    T[row][cg + 8]  = f2bf(f2.x); T[row][cg + 9]  = f2bf(f2.y);
    T[row][cg + 10] = f2bf(f2.z); T[row][cg + 11] = f2bf(f2.w);
    T[row][cg + 12] = f2bf(f3.x); T[row][cg + 13] = f2bf(f3.y);
    T[row][cg + 14] = f2bf(f3.z); T[row][cg + 15] = f2bf(f3.w);
    __syncthreads();
    unsigned short* d = dst + (size_t)(c0 + row) * R + r0 + cg;
    short8 o0, o1;
    #pragma unroll
    for (int k = 0; k < 8; ++k) o0[k] = (short)T[cg + k][row];
    #pragma unroll
    for (int k = 0; k < 8; ++k) o1[k] = (short)T[cg + 8 + k][row];
    *(short8*)d       = o0;
    *(short8*)(d + 8) = o1;
}

// ---------------------------------------------------------------- transpose bf16
__global__ __launch_bounds__(256)
void tr_bf16(unsigned short* __restrict__ dst, const unsigned short* __restrict__ src,
             int R, int C)
{
    __shared__ unsigned short T[64][72];
    const size_t bofs = (size_t)blockIdx.z * (size_t)R * (size_t)C;
    src += bofs; dst += bofs;
    const int t  = threadIdx.x;
    const int r0 = blockIdx.y * 64, c0 = blockIdx.x * 64;
    const int row = t >> 2, cg = (t & 3) * 16;
    const unsigned short* s = src + (size_t)(r0 + row) * C + c0 + cg;
    *(short8*)&T[row][cg]     = *(const short8*)s;
    *(short8*)&T[row][cg + 8] = *(const short8*)(s + 8);
    __syncthreads();
    unsigned short* d = dst + (size_t)(c0 + row) * R + r0 + cg;
    short8 o0, o1;
    #pragma unroll
    for (int k = 0; k < 8; ++k) o0[k] = (short)T[cg + k][row];
    #pragma unroll
    for (int k = 0; k < 8; ++k) o1[k] = (short)T[cg + 8 + k][row];
    *(short8*)d       = o0;
    *(short8*)(d + 8) = o1;
}

// ---------------------------------------------------------------- gather rows (bf16)
__global__ __launch_bounds__(256)
void gather_rows(const unsigned short* __restrict__ xb, const int* __restrict__ sidx,
                 unsigned short* __restrict__ xkg, unsigned short* __restrict__ xvg)
{
    const int blk = blockIdx.x;
    const int b = blk >> 9, j = blk & 511;
    const int t = threadIdx.x;
    int qv = sidx[j];               qv = qv < 0 ? 0 : (qv > LSEQ - 1 ? LSEQ - 1 : qv);
    int cv = qv < SK - 1 ? qv : SK - 1;
    int pv = sidx[cv];              pv = pv < 0 ? 0 : (pv > LSEQ - 1 ? LSEQ - 1 : pv);
    const unsigned int* xs = (const unsigned int*)xb;
    unsigned int* kd = (unsigned int*)xkg;
    unsigned int* vd = (unsigned int*)xvg;
    const size_t dst = ((size_t)b * SK + j) * 256 + t;
    kd[dst] = xs[((size_t)b * LSEQ + pv) * 256 + t];
    vd[dst] = xs[((size_t)b * LSEQ + qv) * 256 + t];
}

// ---------------------------------------------------------------- zero pad rows
__global__ __launch_bounds__(256)
void zero_pad(unsigned short* __restrict__ attpad)
{
    const int i = blockIdx.x * 256 + threadIdx.x;   // 0..4095
    const int b = i >> 9, c = i & 511;
    attpad[(size_t)b * PADROW + c] = 0;
    attpad[(size_t)b * PADROW + (size_t)(LPAD - 1) * 512 + c] = 0;
}

// ---------------------------------------------------------------- GEMM 128x128x32
// MODE 0: bf16 store. MODE 1: conv epilogue (+bias, ELU, MaxPool2 -> bf16).
// MODE 2: +bias, fp32 store.
template<int MODE>
__global__ __launch_bounds__(256)
void gemm128(const unsigned short* __restrict__ A, const unsigned short* __restrict__ Bt,
             const float* __restrict__ bias, void* __restrict__ Cout, int K)
{
    __shared__ unsigned short As[128 * 40];
    __shared__ unsigned short Bs[128 * 40];
    const int t    = threadIdx.x;
    const int n0   = blockIdx.x * 128;
    const int m0   = blockIdx.y * 128;
    const int srow = t >> 1, scg = (t & 1) * 16;
    const int lane = t & 63, wv = t >> 6;
    const int q = lane >> 4, ln = lane & 15;
    const int wm = (wv & 1) * 64, wn = (wv >> 1) * 64;

    const unsigned short* abase;
    if (MODE == 1) {
        const int gr = m0 + srow;
        abase = A + (size_t)(gr >> 12) * PADROW + (size_t)(gr & 4095) * 512;
    } else {
        abase = A + (size_t)(m0 + srow) * K;
    }
    const unsigned short* bbase = Bt + (size_t)(n0 + srow) * K;

    const f32x4 zero = {0.f, 0.f, 0.f, 0.f};
    f32x4 acc[4][4];
    #pragma unroll
    for (int i = 0; i < 4; ++i)
        #pragma unroll
        for (int j = 0; j < 4; ++j) acc[i][j] = zero;

    short8 av0 = *(const short8*)(abase + scg);
    short8 av1 = *(const short8*)(abase + scg + 8);
    short8 bv0 = *(const short8*)(bbase + scg);
    short8 bv1 = *(const short8*)(bbase + scg + 8);

    for (int k0 = 0; k0 < K; k0 += 32) {
        __syncthreads();
        *(short8*)&As[srow * 40 + scg]     = av0;
        *(short8*)&As[srow * 40 + scg + 8] = av1;
        *(short8*)&Bs[srow * 40 + scg]     = bv0;
        *(short8*)&Bs[srow * 40 + scg + 8] = bv1;
        __syncthreads();
        if (k0 + 32 < K) {
            av0 = *(const short8*)(abase + k0 + 32 + scg);
            av1 = *(const short8*)(abase + k0 + 32 + scg + 8);
            bv0 = *(const short8*)(bbase + k0 + 32 + scg);
            bv1 = *(const short8*)(bbase + k0 + 32 + scg + 8);
        }
        short8 af[4], bf[4];
        #pragma unroll
        for (int mt = 0; mt < 4; ++mt)
            af[mt] = *(const short8*)&As[(wm + mt * 16 + ln) * 40 + q * 8];
        #pragma unroll
        for (int nt = 0; nt < 4; ++nt)
            bf[nt] = *(const short8*)&Bs[(wn + nt * 16 + ln) * 40 + q * 8];
        #pragma unroll
        for (int mt = 0; mt < 4; ++mt)
            #pragma unroll
            for (int nt = 0; nt < 4; ++nt)
                acc[mt][nt] = __builtin_amdgcn_mfma_f32_16x16x32_bf16(af[mt], bf[nt], acc[mt][nt], 0, 0, 0);
    }

    if (MODE == 0) {
        unsigned short* C = (unsigned short*)Cout;
        #pragma unroll
        for (int mt = 0; mt < 4; ++mt)
            #pragma unroll
            for (int r = 0; r < 4; ++r) {
                const int grow = m0 + wm + mt * 16 + q * 4 + r;
                unsigned short* cp = C + (size_t)grow * 512 + n0 + wn + ln;
                #pragma unroll
                for (int nt = 0; nt < 4; ++nt) cp[nt * 16] = f2bf(acc[mt][nt][r]);
            }
    } else if (MODE == 2) {
        float* C = (float*)Cout;
        float bb[4];
        #pragma unroll
        for (int nt = 0; nt < 4; ++nt) bb[nt] = bias[n0 + wn + nt * 16 + ln];
        #pragma unroll
        for (int mt = 0; mt < 4; ++mt)
            #pragma unroll
            for (int r = 0; r < 4; ++r) {
                const int grow = m0 + wm + mt * 16 + q * 4 + r;
                float* cp = C + (size_t)grow * 512 + n0 + wn + ln;
                #pragma unroll
                for (int nt = 0; nt < 4; ++nt) cp[nt * 16] = acc[mt][nt][r] + bb[nt];
            }
    } else { // MODE 1
        unsigned short* C = (unsigned short*)Cout;
        float bb[4];
        #pragma unroll
        for (int nt = 0; nt < 4; ++nt) bb[nt] = bias[n0 + wn + nt * 16 + ln];
        #pragma unroll
        for (int mt = 0; mt < 4; ++mt) {
            const int grow = m0 + wm + mt * 16 + q * 4;
            const int b = grow >> 12, l = grow & 4095;
            unsigned short* cp = C + ((size_t)b * 2048 + (l >> 1)) * 512 + n0 + wn + ln;
            #pragma unroll
            for (int nt = 0; nt < 4; ++nt) {
                float v0 = acc[mt][nt][0] + bb[nt]; v0 = v0 > 0.f ? v0 : __expf(v0) - 1.f;
                float v1 = acc[mt][nt][1] + bb[nt]; v1 = v1 > 0.f ? v1 : __expf(v1) - 1.f;
                float v2 = acc[mt][nt][2] + bb[nt]; v2 = v2 > 0.f ? v2 : __expf(v2) - 1.f;
                float v3 = acc[mt][nt][3] + bb[nt]; v3 = v3 > 0.f ? v3 : __expf(v3) - 1.f;
                cp[nt * 16]       = f2bf(fmaxf(v0, v1));
                cp[512 + nt * 16] = f2bf(fmaxf(v2, v3));
            }
        }
    }
}

// ---------------------------------------------------------------- fused attention v3
// BARRIER-FREE flash. grid (L/64, H, B), 256 threads = 4 waves; wave w owns
// q-rows w*16..w*16+15, processes S in 4 chunks of 128 with online softmax.
//
// Trick: scores computed TRANSPOSED  St[s][q] = K·Q^T  (A=K m=s, B=Q n=q).
// C-layout of St: s = quad*4+r, q = ln  ->  per-q softmax state lives at lane
// index ln, reductions over s are shfl_xor(16)+shfl_xor(32) only. P round-trips
// through wave-PRIVATE LDS (8x ds_write_b64) to become the PV A-operand.
// K and V are read from global (L2-resident). No __syncthreads anywhere;
// cross-lane LDS visibility within a wave via s_waitcnt lgkmcnt(0).
__global__ __launch_bounds__(256, 4)
void attn_fused(const unsigned short* __restrict__ xb, const unsigned short* __restrict__ WqT,
                const unsigned short* __restrict__ Kg, const unsigned short* __restrict__ Vt,
                unsigned short* __restrict__ attpad)
{
    __shared__ unsigned short Qs[64][72];     // wave-private rows [wv*16, wv*16+16)
    __shared__ unsigned short Pp[64][136];    // wave-private rows, cols 0..127 per chunk
    const int t = threadIdx.x;
    const int wv = t >> 6, lane = t & 63, q = lane >> 4, ln = lane & 15;
    const int l0 = blockIdx.x * 64, h = blockIdx.y, b = blockIdx.z;
    const f32x4 zero = {0.f, 0.f, 0.f, 0.f};

    // --- phase 0: Q projection (m=16 q-rows, n=64 head cols, k=512)
    f32x4 qacc[4];
    #pragma unroll
    for (int i = 0; i < 4; ++i) qacc[i] = zero;
    const unsigned short* xr = xb + ((size_t)(b * LSEQ + l0 + wv * 16 + ln)) * 512 + q * 8;
    const unsigned short* wqp = WqT + ((size_t)(h * 64 + ln)) * 512 + q * 8;
    for (int ks = 0; ks < 16; ++ks) {
        const short8 ax = *(const short8*)(xr + ks * 32);
        #pragma unroll
        for (int nt = 0; nt < 4; ++nt) {
            const short8 bw = *(const short8*)(wqp + nt * 16 * 512 + ks * 32);
            qacc[nt] = __builtin_amdgcn_mfma_f32_16x16x32_bf16(ax, bw, qacc[nt], 0, 0, 0);
        }
    }
    #pragma unroll
    for (int nt = 0; nt < 4; ++nt)
        #pragma unroll
        for (int r = 0; r < 4; ++r)
            Qs[wv * 16 + q * 4 + r][nt * 16 + ln] = f2bf(qacc[nt][r]);
    asm volatile("s_waitcnt lgkmcnt(0)" ::: "memory");   // wave-internal visibility
    // Q as B-frag for transposed scores: B[n=q=ln][k=d=quad*8+j]
    const short8 bq0 = *(const short8*)&Qs[wv * 16 + ln][q * 8];
    const short8 bq1 = *(const short8*)&Qs[wv * 16 + ln][q * 8 + 32];

    // --- flash state (per q = ln, replicated across quads)
    float m_run = -1e30f, l_run = 0.f;
    f32x4 o[4];     // O C-layout: row q' = quad*4+r, col d = j*16+ln
    #pragma unroll
    for (int j = 0; j < 4; ++j) o[j] = zero;

    const unsigned short* kb = Kg + (size_t)b * SK * 512 + h * 64;
    const unsigned short* vb = Vt + ((size_t)(b * EDIM + h * 64)) * SK;

    for (int c = 0; c < 4; ++c) {
        // scores (transposed): St[s=c*128+nt*16+quad*4+r][q=ln]
        f32x4 st[8];
        const unsigned short* kc = kb + (size_t)(c * 128 + ln) * 512 + q * 8;
        #pragma unroll
        for (int nt = 0; nt < 8; ++nt) {
            const unsigned short* kr = kc + (size_t)(nt * 16) * 512;
            const short8 ak0 = *(const short8*)kr;
            const short8 ak1 = *(const short8*)(kr + 32);
            f32x4 a = zero;
            a = __builtin_amdgcn_mfma_f32_16x16x32_bf16(ak0, bq0, a, 0, 0, 0);
            a = __builtin_amdgcn_mfma_f32_16x16x32_bf16(ak1, bq1, a, 0, 0, 0);
            #pragma unroll
            for (int r = 0; r < 4; ++r) a[r] *= 0.125f;
            st[nt] = a;
        }

        // register softmax over s (32 local values + 2 shuffles)
        float mx = st[0][0];
        #pragma unroll
        for (int nt = 0; nt < 8; ++nt)
            #pragma unroll
            for (int r = 0; r < 4; ++r) mx = fmaxf(mx, st[nt][r]);
        mx = fmaxf(mx, __shfl_xor(mx, 16));
        mx = fmaxf(mx, __shfl_xor(mx, 32));
        const float m_new = fmaxf(m_run, mx);
        const float alpha = __expf(m_run - m_new);
        m_run = m_new;
        float ls = 0.f;
        short4b p4[8];
        #pragma unroll
        for (int nt = 0; nt < 8; ++nt)
            #pragma unroll
            for (int r = 0; r < 4; ++r) {
                const float p = __expf(st[nt][r] - m_new);
                ls += p;
                p4[nt][r] = (short)f2bf(p);
            }
        ls += __shfl_xor(ls, 16);
        ls += __shfl_xor(ls, 32);
        l_run = l_run * alpha + ls;

        // P -> wave-private LDS (C-layout == A-frag rows after transpose)
        #pragma unroll
        for (int nt = 0; nt < 8; ++nt)
            *(short4b*)&Pp[wv * 16 + ln][nt * 16 + q * 4] = p4[nt];

        // rescale O by alpha broadcast to C-layout rows (q' = quad*4+r)
        float ab[4];
        #pragma unroll
        for (int r = 0; r < 4; ++r) ab[r] = __shfl(alpha, q * 4 + r);
        #pragma unroll
        for (int j = 0; j < 4; ++j)
            #pragma unroll
            for (int r = 0; r < 4; ++r) o[j][r] *= ab[r];

        asm volatile("s_waitcnt lgkmcnt(0)" ::: "memory");   // P visible to wave

        // PV: A = P[q=ln][s], B = Vt[d][s], k = 128 chunk
        #pragma unroll
        for (int ks = 0; ks < 4; ++ks) {
            const short8 ap = *(const short8*)&Pp[wv * 16 + ln][ks * 32 + q * 8];
            #pragma unroll
            for (int j = 0; j < 4; ++j) {
                const short8 bv = *(const short8*)(vb + (size_t)(j * 16 + ln) * SK + c * 128 + ks * 32 + q * 8);
                o[j] = __builtin_amdgcn_mfma_f32_16x16x32_bf16(ap, bv, o[j], 0, 0, 0);
            }
        }
    }

    // epilogue: scale rows by 1/l (broadcast to C-layout), store
    const float li = 1.f / l_run;
    float ib[4];
    #pragma unroll
    for (int r = 0; r < 4; ++r) ib[r] = __shfl(li, q * 4 + r);
    #pragma unroll
    for (int j = 0; j < 4; ++j)
        #pragma unroll
        for (int r = 0; r < 4; ++r) {
            const int rl = wv * 16 + q * 4 + r;
            attpad[((size_t)b * PADROW) + (size_t)(l0 + rl + 1) * 512 + h * 64 + j * 16 + ln]
                = f2bf(o[j][r] * ib[r]);
        }
}

// ---------------------------------------------------------------- launcher
extern "C" void kernel_launch(void* const* d_in, const int* in_sizes, int n_in,
                              void* d_out, int out_size, void* d_ws, size_t ws_size,
                              hipStream_t stream)
{
    const float* x    = (const float*)d_in[0];
    const float* Wq   = (const float*)d_in[1];
    const float* Wk   = (const float*)d_in[2];
    const float* Wv   = (const float*)d_in[3];
    const float* cw   = (const float*)d_in[4];   // [1536][512] flat fp32
    const float* cb   = (const float*)d_in[5];
    const float* mw   = (const float*)d_in[6];
    const float* mb2  = (const float*)d_in[7];
    const int*   sidx = (const int*)d_in[8];
    float* out = (float*)d_out;

    char* ws = (char*)d_ws;
    unsigned short* xb    = (unsigned short*)(ws + 0);           // 33,554,432 B
    unsigned short* Pool  = (unsigned short*)(ws + 0);           // alias (xb dead post-attn)
    unsigned short* Pad   = (unsigned short*)(ws + 33554432);    // 33,570,816 B
    unsigned short* xkg   = (unsigned short*)(ws + 33554432);    // alias Pad head
    unsigned short* xvg   = (unsigned short*)(ws + 37748736);    // alias
    unsigned short* Vg    = (unsigned short*)(ws + 41943040);    // alias
    unsigned short* Kg    = (unsigned short*)(ws + 67125248);    //  4,194,304 B
    unsigned short* Vt    = (unsigned short*)(ws + 71319552);    //  4,194,304 B
    unsigned short* WqT   = (unsigned short*)(ws + 75513856);    //    524,288 B
    unsigned short* WkT   = (unsigned short*)(ws + 76038144);
    unsigned short* WvT   = (unsigned short*)(ws + 76562432);
    unsigned short* CombT = (unsigned short*)(ws + 77086720);
    unsigned short* ConvT = (unsigned short*)(ws + 77611008);    // 1,572,864 B -> end 79,183,872

    dim3 blk(256);

    // 0. x -> bf16
    cvt_bf16<<<dim3(8192), blk, 0, stream>>>(x, xb);

    // 1. weight transposes (fp32 -> bf16): dst[N][K] = W[K][N]
    tr_f32_bf16<<<dim3(8, 8),  blk, 0, stream>>>(WqT,   Wq, 512, 512);
    tr_f32_bf16<<<dim3(8, 8),  blk, 0, stream>>>(WkT,   Wk, 512, 512);
    tr_f32_bf16<<<dim3(8, 8),  blk, 0, stream>>>(WvT,   Wv, 512, 512);
    tr_f32_bf16<<<dim3(8, 8),  blk, 0, stream>>>(CombT, mw, 512, 512);
    tr_f32_bf16<<<dim3(8, 24), blk, 0, stream>>>(ConvT, cw, 1536, 512);

    // 2. gathers (xkg/xvg in Pad head; consumed before zero_pad/attn)
    gather_rows<<<dim3(4096), blk, 0, stream>>>(xb, sidx, xkg, xvg);

    // 3. K/V projections (per-batch 512 gathered rows)
    gemm128<0><<<dim3(4, 32), blk, 0, stream>>>(xkg, WkT, nullptr, Kg, 512);
    gemm128<0><<<dim3(4, 32), blk, 0, stream>>>(xvg, WvT, nullptr, Vg, 512);

    // 4. Vt[b][e][s] = Vg[b][s][e]
    tr_bf16<<<dim3(8, 8, 8), blk, 0, stream>>>(Vt, Vg, 512, 512);

    // 5. attention (barrier-free flash; writes Pad rows 1..L)
    zero_pad<<<dim3(16), blk, 0, stream>>>(Pad);
    attn_fused<<<dim3(64, 8, 8), blk, 0, stream>>>(xb, WqT, Kg, Vt, Pad);

    // 6. conv (K=1536) + bias + ELU + pool -> Pool (aliases dead xb)
    gemm128<1><<<dim3(4, 256), blk, 0, stream>>>(Pad, ConvT, cb, Pool, 1536);

    // 7. final dense + bias -> out (fp32)
    gemm128<2><<<dim3(4, 128), blk, 0, stream>>>(Pool, CombT, mb2, out, 512);
}

// Round 6
// 386.950 us; speedup vs baseline: 1.6254x; 1.6254x over previous
//
#include <hip/hip_runtime.h>

// ProbAttention on MI355X (gfx950). Inputs/outputs fp32; compute in bf16 MFMA
// (mfma_f32_16x16x32_bf16, fp32 accumulate). B=8, L=4096, D=512, H=8, DK=64,
// S=512, CONV_K=3, POOL=2.
//
// attn v4: M=128 q-rows/block, K+V chunks staged in LDS shared by all 4 waves
// (8x less L2/L3 traffic than v3), transposed-scores register softmax,
// wave-private P/Q LDS round-trips, register prefetch of next K/V chunk.

typedef __attribute__((ext_vector_type(8))) short  short8;
typedef __attribute__((ext_vector_type(4))) short  short4b;
typedef __attribute__((ext_vector_type(4))) float  f32x4;

#define LSEQ   4096
#define SK     512
#define EDIM   512
#define LPAD   4098            // L + 2
#define PADROW 2098176         // LPAD * 512 (shorts)

static __device__ __forceinline__ float bf2f(unsigned short h) {
    union { unsigned int u; float f; } v; v.u = ((unsigned int)h) << 16; return v.f;
}
static __device__ __forceinline__ unsigned short f2bf(float f) {
    union { float f; unsigned int u; } v; v.f = f;
    unsigned int r = (v.u + 0x7fffu + ((v.u >> 16) & 1u)) >> 16;
    return (unsigned short)r;
}

// ---------------------------------------------------------------- fp32 -> bf16
__global__ __launch_bounds__(256)
void cvt_bf16(const float* __restrict__ src, unsigned short* __restrict__ dst)
{
    const size_t i = ((size_t)blockIdx.x * 256 + threadIdx.x) * 8;
    const float4 a = *(const float4*)(src + i);
    const float4 b = *(const float4*)(src + i + 4);
    short8 o;
    o[0] = (short)f2bf(a.x); o[1] = (short)f2bf(a.y);
    o[2] = (short)f2bf(a.z); o[3] = (short)f2bf(a.w);
    o[4] = (short)f2bf(b.x); o[5] = (short)f2bf(b.y);
    o[6] = (short)f2bf(b.z); o[7] = (short)f2bf(b.w);
    *(short8*)(dst + i) = o;
}

// ---------------------------------------------------------------- transpose fp32 -> bf16
__global__ __launch_bounds__(256)
void tr_f32_bf16(unsigned short* __restrict__ dst, const float* __restrict__ src,
                 int R, int C)
{
    __shared__ unsigned short T[64][72];
    const int t  = threadIdx.x;
    const int r0 = blockIdx.y * 64, c0 = blockIdx.x * 64;
    const int row = t >> 2, cg = (t & 3) * 16;
    const float* s = src + (size_t)(r0 + row) * C + c0 + cg;
    const float4 f0 = *(const float4*)s;
    const float4 f1 = *(const float4*)(s + 4);
    const float4 f2 = *(const float4*)(s + 8);
    const float4 f3 = *(const float4*)(s + 12);
    T[row][cg + 0]  = f2bf(f0.x); T[row][cg + 1]  = f2bf(f0.y);
    T[row][cg + 2]  = f2bf(f0.z); T[row][cg + 3]  = f2bf(f0.w);
    T[row][cg + 4]  = f2bf(f1.x); T[row][cg + 5]  = f2bf(f1.y);
    T[row][cg + 6]  = f2bf(f1.z); T[row][cg + 7]  = f2bf(f1.w);
    T[row][cg + 8]  = f2bf(f2.x); T[row][cg + 9]  = f2bf(f2.y);
    T[row][cg + 10] = f2bf(f2.z); T[row][cg + 11] = f2bf(f2.w);
    T[row][cg + 12] = f2bf(f3.x); T[row][cg + 13] = f2bf(f3.y);
    T[row][cg + 14] = f2bf(f3.z); T[row][cg + 15] = f2bf(f3.w);
    __syncthreads();
    unsigned short* d = dst + (size_t)(c0 + row) * R + r0 + cg;
    short8 o0, o1;
    #pragma unroll
    for (int k = 0; k < 8; ++k) o0[k] = (short)T[cg + k][row];
    #pragma unroll
    for (int k = 0; k < 8; ++k) o1[k] = (short)T[cg + 8 + k][row];
    *(short8*)d       = o0;
    *(short8*)(d + 8) = o1;
}

// ---------------------------------------------------------------- transpose bf16
__global__ __launch_bounds__(256)
void tr_bf16(unsigned short* __restrict__ dst, const unsigned short* __restrict__ src,
             int R, int C)
{
    __shared__ unsigned short T[64][72];
    const size_t bofs = (size_t)blockIdx.z * (size_t)R * (size_t)C;
    src += bofs; dst += bofs;
    const int t  = threadIdx.x;
    const int r0 = blockIdx.y * 64, c0 = blockIdx.x * 64;
    const int row = t >> 2, cg = (t & 3) * 16;
    const unsigned short* s = src + (size_t)(r0 + row) * C + c0 + cg;
    *(short8*)&T[row][cg]     = *(const short8*)s;
    *(short8*)&T[row][cg + 8] = *(const short8*)(s + 8);
    __syncthreads();
    unsigned short* d = dst + (size_t)(c0 + row) * R + r0 + cg;
    short8 o0, o1;
    #pragma unroll
    for (int k = 0; k < 8; ++k) o0[k] = (short)T[cg + k][row];
    #pragma unroll
    for (int k = 0; k < 8; ++k) o1[k] = (short)T[cg + 8 + k][row];
    *(short8*)d       = o0;
    *(short8*)(d + 8) = o1;
}

// ---------------------------------------------------------------- gather rows (bf16)
__global__ __launch_bounds__(256)
void gather_rows(const unsigned short* __restrict__ xb, const int* __restrict__ sidx,
                 unsigned short* __restrict__ xkg, unsigned short* __restrict__ xvg)
{
    const int blk = blockIdx.x;
    const int b = blk >> 9, j = blk & 511;
    const int t = threadIdx.x;
    int qv = sidx[j];               qv = qv < 0 ? 0 : (qv > LSEQ - 1 ? LSEQ - 1 : qv);
    int cv = qv < SK - 1 ? qv : SK - 1;
    int pv = sidx[cv];              pv = pv < 0 ? 0 : (pv > LSEQ - 1 ? LSEQ - 1 : pv);
    const unsigned int* xs = (const unsigned int*)xb;
    unsigned int* kd = (unsigned int*)xkg;
    unsigned int* vd = (unsigned int*)xvg;
    const size_t dst = ((size_t)b * SK + j) * 256 + t;
    kd[dst] = xs[((size_t)b * LSEQ + pv) * 256 + t];
    vd[dst] = xs[((size_t)b * LSEQ + qv) * 256 + t];
}

// ---------------------------------------------------------------- zero pad rows
__global__ __launch_bounds__(256)
void zero_pad(unsigned short* __restrict__ attpad)
{
    const int i = blockIdx.x * 256 + threadIdx.x;   // 0..4095
    const int b = i >> 9, c = i & 511;
    attpad[(size_t)b * PADROW + c] = 0;
    attpad[(size_t)b * PADROW + (size_t)(LPAD - 1) * 512 + c] = 0;
}

// ---------------------------------------------------------------- GEMM 128x128x32
// MODE 0: bf16 store. MODE 1: conv epilogue (+bias, ELU, MaxPool2 -> bf16).
// MODE 2: +bias, fp32 store.
template<int MODE>
__global__ __launch_bounds__(256)
void gemm128(const unsigned short* __restrict__ A, const unsigned short* __restrict__ Bt,
             const float* __restrict__ bias, void* __restrict__ Cout, int K)
{
    __shared__ unsigned short As[128 * 40];
    __shared__ unsigned short Bs[128 * 40];
    const int t    = threadIdx.x;
    const int n0   = blockIdx.x * 128;
    const int m0   = blockIdx.y * 128;
    const int srow = t >> 1, scg = (t & 1) * 16;
    const int lane = t & 63, wv = t >> 6;
    const int q = lane >> 4, ln = lane & 15;
    const int wm = (wv & 1) * 64, wn = (wv >> 1) * 64;

    const unsigned short* abase;
    if (MODE == 1) {
        const int gr = m0 + srow;
        abase = A + (size_t)(gr >> 12) * PADROW + (size_t)(gr & 4095) * 512;
    } else {
        abase = A + (size_t)(m0 + srow) * K;
    }
    const unsigned short* bbase = Bt + (size_t)(n0 + srow) * K;

    const f32x4 zero = {0.f, 0.f, 0.f, 0.f};
    f32x4 acc[4][4];
    #pragma unroll
    for (int i = 0; i < 4; ++i)
        #pragma unroll
        for (int j = 0; j < 4; ++j) acc[i][j] = zero;

    short8 av0 = *(const short8*)(abase + scg);
    short8 av1 = *(const short8*)(abase + scg + 8);
    short8 bv0 = *(const short8*)(bbase + scg);
    short8 bv1 = *(const short8*)(bbase + scg + 8);

    for (int k0 = 0; k0 < K; k0 += 32) {
        __syncthreads();
        *(short8*)&As[srow * 40 + scg]     = av0;
        *(short8*)&As[srow * 40 + scg + 8] = av1;
        *(short8*)&Bs[srow * 40 + scg]     = bv0;
        *(short8*)&Bs[srow * 40 + scg + 8] = bv1;
        __syncthreads();
        if (k0 + 32 < K) {
            av0 = *(const short8*)(abase + k0 + 32 + scg);
            av1 = *(const short8*)(abase + k0 + 32 + scg + 8);
            bv0 = *(const short8*)(bbase + k0 + 32 + scg);
            bv1 = *(const short8*)(bbase + k0 + 32 + scg + 8);
        }
        short8 af[4], bf[4];
        #pragma unroll
        for (int mt = 0; mt < 4; ++mt)
            af[mt] = *(const short8*)&As[(wm + mt * 16 + ln) * 40 + q * 8];
        #pragma unroll
        for (int nt = 0; nt < 4; ++nt)
            bf[nt] = *(const short8*)&Bs[(wn + nt * 16 + ln) * 40 + q * 8];
        #pragma unroll
        for (int mt = 0; mt < 4; ++mt)
            #pragma unroll
            for (int nt = 0; nt < 4; ++nt)
                acc[mt][nt] = __builtin_amdgcn_mfma_f32_16x16x32_bf16(af[mt], bf[nt], acc[mt][nt], 0, 0, 0);
    }

    if (MODE == 0) {
        unsigned short* C = (unsigned short*)Cout;
        #pragma unroll
        for (int mt = 0; mt < 4; ++mt)
            #pragma unroll
            for (int r = 0; r < 4; ++r) {
                const int grow = m0 + wm + mt * 16 + q * 4 + r;
                unsigned short* cp = C + (size_t)grow * 512 + n0 + wn + ln;
                #pragma unroll
                for (int nt = 0; nt < 4; ++nt) cp[nt * 16] = f2bf(acc[mt][nt][r]);
            }
    } else if (MODE == 2) {
        float* C = (float*)Cout;
        float bb[4];
        #pragma unroll
        for (int nt = 0; nt < 4; ++nt) bb[nt] = bias[n0 + wn + nt * 16 + ln];
        #pragma unroll
        for (int mt = 0; mt < 4; ++mt)
            #pragma unroll
            for (int r = 0; r < 4; ++r) {
                const int grow = m0 + wm + mt * 16 + q * 4 + r;
                float* cp = C + (size_t)grow * 512 + n0 + wn + ln;
                #pragma unroll
                for (int nt = 0; nt < 4; ++nt) cp[nt * 16] = acc[mt][nt][r] + bb[nt];
            }
    } else { // MODE 1
        unsigned short* C = (unsigned short*)Cout;
        float bb[4];
        #pragma unroll
        for (int nt = 0; nt < 4; ++nt) bb[nt] = bias[n0 + wn + nt * 16 + ln];
        #pragma unroll
        for (int mt = 0; mt < 4; ++mt) {
            const int grow = m0 + wm + mt * 16 + q * 4;
            const int b = grow >> 12, l = grow & 4095;
            unsigned short* cp = C + ((size_t)b * 2048 + (l >> 1)) * 512 + n0 + wn + ln;
            #pragma unroll
            for (int nt = 0; nt < 4; ++nt) {
                float v0 = acc[mt][nt][0] + bb[nt]; v0 = v0 > 0.f ? v0 : __expf(v0) - 1.f;
                float v1 = acc[mt][nt][1] + bb[nt]; v1 = v1 > 0.f ? v1 : __expf(v1) - 1.f;
                float v2 = acc[mt][nt][2] + bb[nt]; v2 = v2 > 0.f ? v2 : __expf(v2) - 1.f;
                float v3 = acc[mt][nt][3] + bb[nt]; v3 = v3 > 0.f ? v3 : __expf(v3) - 1.f;
                cp[nt * 16]       = f2bf(fmaxf(v0, v1));
                cp[512 + nt * 16] = f2bf(fmaxf(v2, v3));
            }
        }
    }
}

// ---------------------------------------------------------------- fused attention v4
// grid (L/128, H, B), 256 threads = 4 waves; wave w owns 32 q-rows (2 tiles).
// S in 4 chunks of 128, online softmax (transposed scores, per-q state at ln).
// K chunk (128x64) and V chunk (64x128) staged in LDS, SHARED by all waves;
// next chunk register-prefetched during softmax/PV. Q/P round-trips use
// wave-private rows of Pp. LDS = 18,432 + 17,408 + 34,816 = 70,656 B.
__global__ __launch_bounds__(256, 2)
void attn_fused(const unsigned short* __restrict__ xb, const unsigned short* __restrict__ WqT,
                const unsigned short* __restrict__ Kg, const unsigned short* __restrict__ Vt,
                unsigned short* __restrict__ attpad)
{
    __shared__ unsigned short Ks[128][72];
    __shared__ unsigned short Vs[64][136];
    __shared__ unsigned short Pp[128][136];   // P per chunk; also Q round-trip
    const int t = threadIdx.x;
    const int wv = t >> 6, lane = t & 63, q = lane >> 4, ln = lane & 15;
    const int l0 = blockIdx.x * 128, h = blockIdx.y, b = blockIdx.z;
    const int qr0 = wv * 32;
    const f32x4 zero = {0.f, 0.f, 0.f, 0.f};

    // staging maps
    const unsigned short* kgb = Kg + (size_t)b * SK * 512 + h * 64;        // + s*512 + e
    const unsigned short* vtb = Vt + ((size_t)(b * EDIM + h * 64)) * SK;   // + d*SK + s
    const int ksr = t >> 1, ksc = (t & 1) * 32;    // K: row s, 32-short half
    const int vsr = t >> 2, vsc = (t & 3) * 32;    // V: row d, 32-short quarter

    // prefetch chunk 0 (flies during Q projection)
    short8 kp0, kp1, kp2, kp3, vp0, vp1, vp2, vp3;
    {
        const unsigned short* ks = kgb + (size_t)ksr * 512 + ksc;
        kp0 = *(const short8*)ks;        kp1 = *(const short8*)(ks + 8);
        kp2 = *(const short8*)(ks + 16); kp3 = *(const short8*)(ks + 24);
        const unsigned short* vs = vtb + (size_t)vsr * SK + vsc;
        vp0 = *(const short8*)vs;        vp1 = *(const short8*)(vs + 8);
        vp2 = *(const short8*)(vs + 16); vp3 = *(const short8*)(vs + 24);
    }

    // --- Q projection: rows qr0 + g*16 + ln (g=0,1), 64 head cols, k=512
    f32x4 qacc[2][4];
    #pragma unroll
    for (int g = 0; g < 2; ++g)
        #pragma unroll
        for (int nt = 0; nt < 4; ++nt) qacc[g][nt] = zero;
    const unsigned short* xr0 = xb + ((size_t)(b * LSEQ + l0 + qr0 + ln)) * 512 + q * 8;
    const unsigned short* xr1 = xr0 + (size_t)16 * 512;
    const unsigned short* wqp = WqT + ((size_t)(h * 64 + ln)) * 512 + q * 8;
    for (int ks = 0; ks < 16; ++ks) {
        const short8 ax0 = *(const short8*)(xr0 + ks * 32);
        const short8 ax1 = *(const short8*)(xr1 + ks * 32);
        #pragma unroll
        for (int nt = 0; nt < 4; ++nt) {
            const short8 bw = *(const short8*)(wqp + nt * 16 * 512 + ks * 32);
            qacc[0][nt] = __builtin_amdgcn_mfma_f32_16x16x32_bf16(ax0, bw, qacc[0][nt], 0, 0, 0);
            qacc[1][nt] = __builtin_amdgcn_mfma_f32_16x16x32_bf16(ax1, bw, qacc[1][nt], 0, 0, 0);
        }
    }
    #pragma unroll
    for (int g = 0; g < 2; ++g)
        #pragma unroll
        for (int nt = 0; nt < 4; ++nt)
            #pragma unroll
            for (int r = 0; r < 4; ++r)
                Pp[qr0 + g * 16 + q * 4 + r][nt * 16 + ln] = f2bf(qacc[g][nt][r]);
    asm volatile("s_waitcnt lgkmcnt(0)" ::: "memory");   // wave-private round trip
    short8 bq[2][2];
    #pragma unroll
    for (int g = 0; g < 2; ++g) {
        bq[g][0] = *(const short8*)&Pp[qr0 + g * 16 + ln][q * 8];
        bq[g][1] = *(const short8*)&Pp[qr0 + g * 16 + ln][q * 8 + 32];
    }

    // --- flash state (per q-col = ln, per group g; replicated across quads)
    float m_run[2] = {-1e30f, -1e30f}, l_run[2] = {0.f, 0.f};
    f32x4 o[2][4];
    #pragma unroll
    for (int g = 0; g < 2; ++g)
        #pragma unroll
        for (int j = 0; j < 4; ++j) o[g][j] = zero;

    for (int c = 0; c < 4; ++c) {
        // store staged chunk (regs were prefetched)
        *(short8*)&Ks[ksr][ksc]      = kp0;  *(short8*)&Ks[ksr][ksc + 8]  = kp1;
        *(short8*)&Ks[ksr][ksc + 16] = kp2;  *(short8*)&Ks[ksr][ksc + 24] = kp3;
        *(short8*)&Vs[vsr][vsc]      = vp0;  *(short8*)&Vs[vsr][vsc + 8]  = vp1;
        *(short8*)&Vs[vsr][vsc + 16] = vp2;  *(short8*)&Vs[vsr][vsc + 24] = vp3;
        __syncthreads();   // A: Ks/Vs ready

        // scores (transposed): St[s = mt*16+quad*4+r][qcol = g*16+ln]
        f32x4 st[8][2];
        #pragma unroll
        for (int mt = 0; mt < 8; ++mt) {
            const short8 ak0 = *(const short8*)&Ks[mt * 16 + ln][q * 8];
            const short8 ak1 = *(const short8*)&Ks[mt * 16 + ln][q * 8 + 32];
            #pragma unroll
            for (int g = 0; g < 2; ++g) {
                f32x4 a = zero;
                a = __builtin_amdgcn_mfma_f32_16x16x32_bf16(ak0, bq[g][0], a, 0, 0, 0);
                a = __builtin_amdgcn_mfma_f32_16x16x32_bf16(ak1, bq[g][1], a, 0, 0, 0);
                #pragma unroll
                for (int r = 0; r < 4; ++r) a[r] *= 0.125f;
                st[mt][g] = a;
            }
        }

        // register online softmax per group
        float alpha_[2];
        #pragma unroll
        for (int g = 0; g < 2; ++g) {
            float mx = st[0][g][0];
            #pragma unroll
            for (int mt = 0; mt < 8; ++mt)
                #pragma unroll
                for (int r = 0; r < 4; ++r) mx = fmaxf(mx, st[mt][g][r]);
            mx = fmaxf(mx, __shfl_xor(mx, 16));
            mx = fmaxf(mx, __shfl_xor(mx, 32));
            const float m_new = fmaxf(m_run[g], mx);
            alpha_[g] = __expf(m_run[g] - m_new);
            m_run[g] = m_new;
            float ls = 0.f;
            #pragma unroll
            for (int mt = 0; mt < 8; ++mt) {
                short4b p4;
                #pragma unroll
                for (int r = 0; r < 4; ++r) {
                    const float p = __expf(st[mt][g][r] - m_new);
                    ls += p;
                    p4[r] = (short)f2bf(p);
                }
                *(short4b*)&Pp[qr0 + g * 16 + ln][mt * 16 + q * 4] = p4;
            }
            ls += __shfl_xor(ls, 16);
            ls += __shfl_xor(ls, 32);
            l_run[g] = l_run[g] * alpha_[g] + ls;
        }

        // rescale O (rows q' = quad*4+r of tile g)
        #pragma unroll
        for (int g = 0; g < 2; ++g) {
            #pragma unroll
            for (int r = 0; r < 4; ++r) {
                const float ab = __shfl(alpha_[g], q * 4 + r);
                #pragma unroll
                for (int j = 0; j < 4; ++j) o[g][j][r] *= ab;
            }
        }

        // prefetch next chunk into regs (overlaps PV)
        if (c < 3) {
            const unsigned short* ks = kgb + (size_t)((c + 1) * 128 + ksr) * 512 + ksc;
            kp0 = *(const short8*)ks;        kp1 = *(const short8*)(ks + 8);
            kp2 = *(const short8*)(ks + 16); kp3 = *(const short8*)(ks + 24);
            const unsigned short* vs = vtb + (size_t)vsr * SK + (c + 1) * 128 + vsc;
            vp0 = *(const short8*)vs;        vp1 = *(const short8*)(vs + 8);
            vp2 = *(const short8*)(vs + 16); vp3 = *(const short8*)(vs + 24);
        }

        asm volatile("s_waitcnt lgkmcnt(0)" ::: "memory");   // P visible to wave

        // PV: A = P rows (q), B = Vs rows (d), k = 128 chunk
        #pragma unroll
        for (int ks2 = 0; ks2 < 4; ++ks2) {
            const short8 ap0 = *(const short8*)&Pp[qr0 + ln][ks2 * 32 + q * 8];
            const short8 ap1 = *(const short8*)&Pp[qr0 + 16 + ln][ks2 * 32 + q * 8];
            #pragma unroll
            for (int j = 0; j < 4; ++j) {
                const short8 bv = *(const short8*)&Vs[j * 16 + ln][ks2 * 32 + q * 8];
                o[0][j] = __builtin_amdgcn_mfma_f32_16x16x32_bf16(ap0, bv, o[0][j], 0, 0, 0);
                o[1][j] = __builtin_amdgcn_mfma_f32_16x16x32_bf16(ap1, bv, o[1][j], 0, 0, 0);
            }
        }
        __syncthreads();   // B: Ks/Vs reads done before restage
    }

    // epilogue: scale by 1/l, store rows l0+qr0+g*16+q*4+r (+1 pad offset)
    #pragma unroll
    for (int g = 0; g < 2; ++g) {
        const float li = 1.f / l_run[g];
        #pragma unroll
        for (int r = 0; r < 4; ++r) {
            const float ib = __shfl(li, q * 4 + r);
            const int rl = qr0 + g * 16 + q * 4 + r;
            #pragma unroll
            for (int j = 0; j < 4; ++j)
                attpad[((size_t)b * PADROW) + (size_t)(l0 + rl + 1) * 512 + h * 64 + j * 16 + ln]
                    = f2bf(o[g][j][r] * ib);
        }
    }
}

// ---------------------------------------------------------------- launcher
extern "C" void kernel_launch(void* const* d_in, const int* in_sizes, int n_in,
                              void* d_out, int out_size, void* d_ws, size_t ws_size,
                              hipStream_t stream)
{
    const float* x    = (const float*)d_in[0];
    const float* Wq   = (const float*)d_in[1];
    const float* Wk   = (const float*)d_in[2];
    const float* Wv   = (const float*)d_in[3];
    const float* cw   = (const float*)d_in[4];   // [1536][512] flat fp32
    const float* cb   = (const float*)d_in[5];
    const float* mw   = (const float*)d_in[6];
    const float* mb2  = (const float*)d_in[7];
    const int*   sidx = (const int*)d_in[8];
    float* out = (float*)d_out;

    char* ws = (char*)d_ws;
    unsigned short* xb    = (unsigned short*)(ws + 0);           // 33,554,432 B
    unsigned short* Pool  = (unsigned short*)(ws + 0);           // alias (xb dead post-attn)
    unsigned short* Pad   = (unsigned short*)(ws + 33554432);    // 33,570,816 B
    unsigned short* xkg   = (unsigned short*)(ws + 33554432);    // alias Pad head
    unsigned short* xvg   = (unsigned short*)(ws + 37748736);    // alias
    unsigned short* Vg    = (unsigned short*)(ws + 41943040);    // alias
    unsigned short* Kg    = (unsigned short*)(ws + 67125248);    //  4,194,304 B
    unsigned short* Vt    = (unsigned short*)(ws + 71319552);    //  4,194,304 B
    unsigned short* WqT   = (unsigned short*)(ws + 75513856);    //    524,288 B
    unsigned short* WkT   = (unsigned short*)(ws + 76038144);
    unsigned short* WvT   = (unsigned short*)(ws + 76562432);
    unsigned short* CombT = (unsigned short*)(ws + 77086720);
    unsigned short* ConvT = (unsigned short*)(ws + 77611008);    // 1,572,864 B -> end 79,183,872

    dim3 blk(256);

    // 0. x -> bf16
    cvt_bf16<<<dim3(8192), blk, 0, stream>>>(x, xb);

    // 1. weight transposes (fp32 -> bf16): dst[N][K] = W[K][N]
    tr_f32_bf16<<<dim3(8, 8),  blk, 0, stream>>>(WqT,   Wq, 512, 512);
    tr_f32_bf16<<<dim3(8, 8),  blk, 0, stream>>>(WkT,   Wk, 512, 512);
    tr_f32_bf16<<<dim3(8, 8),  blk, 0, stream>>>(WvT,   Wv, 512, 512);
    tr_f32_bf16<<<dim3(8, 8),  blk, 0, stream>>>(CombT, mw, 512, 512);
    tr_f32_bf16<<<dim3(8, 24), blk, 0, stream>>>(ConvT, cw, 1536, 512);

    // 2. gathers (xkg/xvg in Pad head; consumed before zero_pad/attn)
    gather_rows<<<dim3(4096), blk, 0, stream>>>(xb, sidx, xkg, xvg);

    // 3. K/V projections (per-batch 512 gathered rows)
    gemm128<0><<<dim3(4, 32), blk, 0, stream>>>(xkg, WkT, nullptr, Kg, 512);
    gemm128<0><<<dim3(4, 32), blk, 0, stream>>>(xvg, WvT, nullptr, Vg, 512);

    // 4. Vt[b][e][s] = Vg[b][s][e]
    tr_bf16<<<dim3(8, 8, 8), blk, 0, stream>>>(Vt, Vg, 512, 512);

    // 5. attention (M=128 flash, LDS-shared K/V; writes Pad rows 1..L)
    zero_pad<<<dim3(16), blk, 0, stream>>>(Pad);
    attn_fused<<<dim3(32, 8, 8), blk, 0, stream>>>(xb, WqT, Kg, Vt, Pad);

    // 6. conv (K=1536) + bias + ELU + pool -> Pool (aliases dead xb)
    gemm128<1><<<dim3(4, 256), blk, 0, stream>>>(Pad, ConvT, cb, Pool, 1536);

    // 7. final dense + bias -> out (fp32)
    gemm128<2><<<dim3(4, 128), blk, 0, stream>>>(Pool, CombT, mb2, out, 512);
}